// Round 8
// baseline (336.746 us; speedup 1.0000x reference)
//
#include <hip/hip_runtime.h>
#include <hip/hip_bf16.h>

// Problem constants
#define BB 2
#define CC 256
#define HH 96
#define WW 96
#define HWP (HH*WW)        // 9216
#define NTOT (BB*HWP)      // 18432 flattened (b,p)
#define K1 2304            // 256*9, GEMM K for both convs
#define NKT 36             // K1/64 k-steps

// d_out layout: logits[2,1,96,96], bbox[2,4,96,96], shape[2,2,96,96], loc[2,1,96,96]
#define OUT_LOGITS 0
#define OUT_BBOX   (2*1*HWP)
#define OUT_SHAPE  (OUT_BBOX + 2*4*HWP)
#define OUT_LOC    (OUT_SHAPE + 2*2*HWP)

typedef __attribute__((ext_vector_type(8))) short short8v;   // 8 bf16 (4 VGPRs)
typedef __attribute__((ext_vector_type(4))) float f32x4;

typedef const __attribute__((address_space(1))) void* gptr_t;
typedef __attribute__((address_space(3))) void* lptr_t;
#define GLOAD16(g, l) __builtin_amdgcn_global_load_lds((gptr_t)(g), (lptr_t)(l), 16, 0, 0)

__device__ __forceinline__ float bf2f(unsigned short u) {
    return __uint_as_float(((unsigned)u) << 16);
}
__device__ __forceinline__ unsigned short f2bf(float f) {
    unsigned u = __float_as_uint(f);
    u += 0x7FFFu + ((u >> 16) & 1u);           // round-to-nearest-even
    return (unsigned short)(u >> 16);
}

// ------- prep: weights -> bf16, BOTH in k = kk*256+ci order; zero page ------
__global__ __launch_bounds__(256) void prep_kernel(
    const float* __restrict__ conv_w, const float* __restrict__ adapt_w,
    unsigned short* __restrict__ W1, unsigned short* __restrict__ W2,
    unsigned short* __restrict__ zp)
{
    const int t = blockIdx.x * 256 + threadIdx.x;
    if (t < 1024) zp[t] = 0;                    // zero page (ws is re-poisoned!)
    if (t < CC * K1) {
        const int co = t / K1, r = t % K1;
        const int kk = r >> 8, ci = r & 255;    // k = kk*256+ci
        W1[t] = f2bf(conv_w[co * K1 + ci * 9 + kk]);
        W2[t] = f2bf(adapt_w[co * K1 + ci * 9 + kk]);
    }
}

// ------------- transpose feature [b][c][p] fp32 -> f_cf [b][p][c] bf16 ------
// grid (144, 4, 2): channel-group split across blockIdx.y (pure permutation).
__global__ __launch_bounds__(256) void transpose_kernel(
    const float* __restrict__ f, unsigned short* __restrict__ fcf)
{
    __shared__ unsigned short tile[64][66];     // +2 pad: conflict-free col reads
    const int p0 = blockIdx.x * 64;
    const int cc = blockIdx.y;
    const int b  = blockIdx.z;
    const int tx = threadIdx.x & 63, ty = threadIdx.x >> 6;
#pragma unroll
    for (int ii = 0; ii < 16; ii++) {
        const int cl = ii * 4 + ty;
        tile[cl][tx] = f2bf(f[((size_t)b * CC + cc * 64 + cl) * HWP + p0 + tx]);
    }
    __syncthreads();
#pragma unroll
    for (int ii = 0; ii < 16; ii++) {
        const int pl = ii * 4 + ty;
        fcf[((size_t)(b * HWP + p0 + pl)) * CC + cc * 64 + tx] = tile[tx][pl];
    }
}

// --------- GEMM1 (R3-verbatim, passed): t = relu(W1 x im2col(f_cf) + bias) --
// 128M x 64N tile, BK=64, 4 waves (2x2), 16x16x32 MFMA, global_load_lds.
__global__ __launch_bounds__(256) void gemm1_kernel(
    const unsigned short* __restrict__ W1, const unsigned short* __restrict__ fcf,
    const float* __restrict__ bias, const unsigned short* __restrict__ zp,
    unsigned short* __restrict__ tcf)
{
    __shared__ short As[8192];                  // 128 rows x 64 k = 16 KB
    __shared__ short Bs[4096];                  // 64 rows x 64 k = 8 KB
    const int tid  = threadIdx.x;
    const int lane = tid & 63, w = tid >> 6;
    const int quad = lane >> 4, r15 = lane & 15;
    const int n0  = blockIdx.x * 64;            // flattened (b,p); 9216%64==0
    const int co0 = blockIdx.y * 128;
    const int wm = w >> 1, wn = w & 1;

    const int nb = n0 + lane;
    const int b  = nb / HWP;
    const int p  = nb - b * HWP;
    const int y = p / WW, x = p % WW;

    f32x4 acc[4][2];
#pragma unroll
    for (int i = 0; i < 4; i++)
#pragma unroll
        for (int j = 0; j < 2; j++) acc[i][j] = (f32x4){0.f, 0.f, 0.f, 0.f};

    for (int kt = 0; kt < NKT; kt++) {
        const int k0 = kt * 64;
#pragma unroll
        for (int i = 0; i < 4; i++) {           // A: 4 chunks/thread
            const int kc    = w * 2 + (i >> 1);
            const int row   = ((i & 1) << 6) + lane;
            const int sbase = w * 256 + i * 64;
            GLOAD16(W1 + (size_t)(co0 + row) * K1 + k0 + kc * 8, &As[sbase * 8]);
        }
#pragma unroll
        for (int i = 0; i < 2; i++) {           // B: 2 chunks/thread, implicit im2col
            const int kc    = w * 2 + i;
            const int sbase = w * 128 + i * 64;
            const int k   = k0 + kc * 8;
            const int kk  = k >> 8;
            const int ci0 = k & 255;
            const int yy = y + kk / 3 - 1, xx = x + kk % 3 - 1;
            const bool ok = (yy >= 0) && (yy < HH) && (xx >= 0) && (xx < WW);
            const unsigned short* gb = ok
                ? fcf + ((size_t)(b * HWP + yy * WW + xx)) * CC + ci0
                : zp;
            GLOAD16(gb, &Bs[sbase * 8]);
        }
        __syncthreads();
#pragma unroll
        for (int ks = 0; ks < 2; ks++) {
            short8v a[4], bf[2];
#pragma unroll
            for (int i = 0; i < 4; i++)
                a[i] = *(const short8v*)&As[(((ks * 4 + quad) * 128) + wm * 64 + i * 16 + r15) * 8];
#pragma unroll
            for (int j = 0; j < 2; j++)
                bf[j] = *(const short8v*)&Bs[(((ks * 4 + quad) * 64) + wn * 32 + j * 16 + r15) * 8];
#pragma unroll
            for (int i = 0; i < 4; i++)
#pragma unroll
                for (int j = 0; j < 2; j++)
                    acc[i][j] = __builtin_amdgcn_mfma_f32_16x16x32_bf16(a[i], bf[j], acc[i][j], 0, 0, 0);
        }
        __syncthreads();
    }
    // epilogue: bias + relu -> t_cf[n][c] bf16 (C/D map: col=lane&15, row=quad*4+reg)
#pragma unroll
    for (int i = 0; i < 4; i++) {
        const int m = co0 + wm * 64 + i * 16 + quad * 4;
        const float b0 = bias[m], b1 = bias[m + 1], b2 = bias[m + 2], b3 = bias[m + 3];
#pragma unroll
        for (int j = 0; j < 2; j++) {
            const int n = n0 + wn * 32 + j * 16 + r15;
            ushort4 st;
            st.x = f2bf(fmaxf(acc[i][j][0] + b0, 0.f));
            st.y = f2bf(fmaxf(acc[i][j][1] + b1, 0.f));
            st.z = f2bf(fmaxf(acc[i][j][2] + b2, 0.f));
            st.w = f2bf(fmaxf(acc[i][j][3] + b3, 0.f));
            *(ushort4*)(tcf + (size_t)n * CC + m) = st;
        }
    }
}

// ---- heads1 (R5-verbatim): loc/shape -> out; (s0,s1) per pixel -> ws -------
__global__ __launch_bounds__(256) void heads1_kernel(
    const unsigned short* __restrict__ tcf,
    const float* __restrict__ loc_w, const float* __restrict__ loc_b,
    const float* __restrict__ shape_w, const float* __restrict__ shape_b,
    float* __restrict__ out, float* __restrict__ s0s1)
{
    const int p = blockIdx.x * 256 + threadIdx.x;
    const int b = blockIdx.y;
    const unsigned short* row = tcf + (size_t)(b * HWP + p) * CC;
    float aloc = 0.f, s0 = 0.f, s1 = 0.f;
    for (int c = 0; c < CC; c += 8) {
        short8v v = *(const short8v*)&row[c];
#pragma unroll
        for (int k = 0; k < 8; k++) {
            const float fv = bf2f((unsigned short)v[k]);
            aloc = fmaf(loc_w[c + k], fv, aloc);
            s0   = fmaf(shape_w[c + k], fv, s0);
            s1   = fmaf(shape_w[CC + c + k], fv, s1);
        }
    }
    aloc += loc_b[0]; s0 += shape_b[0]; s1 += shape_b[1];
    out[OUT_LOC + b * HWP + p] = aloc;
    out[OUT_SHAPE + (b * 2 + 0) * HWP + p] = s0;
    out[OUT_SHAPE + (b * 2 + 1) * HWP + p] = s1;
    *(float2*)&s0s1[2 * (b * HWP + p)] = make_float2(s0, s1);
}

// ---- fused GEMM2: ta = relu(W2 x deform-sampled(tcf)) ----------------------
// M=256 (full co in ONE block; wave w owns co-quarter w*64) x N=32, BK=64.
// Sampling math, B LDS layout (pr*9+kc), and per-element rounding are
// VERBATIM R5 (passed). Only A staging (8 GLOAD16/thread into 32 KB LDS) and
// the co->wave mapping changed, halving the duplicated bilinear sampling.
__global__ __launch_bounds__(256) void gemm2_fused_kernel(
    const unsigned short* __restrict__ W2, const unsigned short* __restrict__ tcf,
    const float* __restrict__ s0s1, const float* __restrict__ offset_w,
    unsigned short* __restrict__ tacf)
{
    __shared__ short As[16384];                 // 8 kc-chunks x 256 rows x 16B = 32 KB
    __shared__ short Bs[32 * 9 * 8];            // R5 padded layout, 4.6 KB
    const int tid  = threadIdx.x;
    const int lane = tid & 63, w = tid >> 6;
    const int quad = lane >> 4, r15 = lane & 15;
    const int n0  = blockIdx.x * 32;

    // sampler mapping (R5): thread -> (pixel pr, 8-ch chunk kc)
    const int pr = tid >> 3, kc = tid & 7;
    const int nb = n0 + pr;
    const int b  = nb / HWP;
    const int p  = nb - b * HWP;
    const int y = p / WW, x = p % WW;
    const float2 s01 = *(const float2*)&s0s1[2 * nb];
    const unsigned short* tb = tcf + (size_t)b * HWP * CC;

    f32x4 acc[4][2];
#pragma unroll
    for (int i = 0; i < 4; i++)
#pragma unroll
        for (int j = 0; j < 2; j++) acc[i][j] = (f32x4){0.f, 0.f, 0.f, 0.f};

    for (int kt = 0; kt < NKT; kt++) {
        const int k0 = kt * 64;
        const int kk = kt >> 2, g = kt & 3;
        // A: wave w stages kc-chunks {2w, 2w+1} x all 256 rows (slot = kc*256+row)
#pragma unroll
        for (int i = 0; i < 8; i++) {
            const int kca   = w * 2 + (i >> 2);
            const int rr    = (i & 3) * 64;          // + lane via DMA
            const int sbase = kca * 256 + rr;
            GLOAD16(W2 + (size_t)(rr + lane) * K1 + k0 + kca * 8, &As[sbase * 8]);
        }
        // B: bilinear sample of 8 channels (R5-verbatim math)
        {
            const int o_dy = (g * 9 + kk) * 2, o_dx = o_dy + 1;
            const float dy = fmaf(offset_w[o_dy * 2], s01.x, offset_w[o_dy * 2 + 1] * s01.y);
            const float dx = fmaf(offset_w[o_dx * 2], s01.x, offset_w[o_dx * 2 + 1] * s01.y);
            const float py = (float)(y + kk / 3 - 1) + dy;
            const float px = (float)(x + kk % 3 - 1) + dx;
            const float y0f = floorf(py), x0f = floorf(px);
            const float wy = py - y0f, wx = px - x0f;
            const int y0 = (int)y0f, x0 = (int)x0f;
            const int y1 = y0 + 1, x1 = x0 + 1;
            const bool vy0 = (y0 >= 0) && (y0 < HH), vy1 = (y1 >= 0) && (y1 < HH);
            const bool vx0 = (x0 >= 0) && (x0 < WW), vx1 = (x1 >= 0) && (x1 < WW);
            const int y0c = min(max(y0, 0), HH - 1), y1c = min(max(y1, 0), HH - 1);
            const int x0c = min(max(x0, 0), WW - 1), x1c = min(max(x1, 0), WW - 1);
            const float w00 = (vy0 && vx0) ? (1.f - wy) * (1.f - wx) : 0.f;
            const float w01 = (vy0 && vx1) ? (1.f - wy) * wx         : 0.f;
            const float w10 = (vy1 && vx0) ? wy * (1.f - wx)         : 0.f;
            const float w11 = (vy1 && vx1) ? wy * wx                 : 0.f;
            const int ch = g * 64 + kc * 8;
            const short8v v00 = *(const short8v*)(tb + (size_t)(y0c * WW + x0c) * CC + ch);
            const short8v v01 = *(const short8v*)(tb + (size_t)(y0c * WW + x1c) * CC + ch);
            const short8v v10 = *(const short8v*)(tb + (size_t)(y1c * WW + x0c) * CC + ch);
            const short8v v11 = *(const short8v*)(tb + (size_t)(y1c * WW + x1c) * CC + ch);
            short8v r;
#pragma unroll
            for (int e = 0; e < 8; e++) {
                float val = w00 * bf2f((unsigned short)v00[e]);
                val = fmaf(w01, bf2f((unsigned short)v01[e]), val);
                val = fmaf(w10, bf2f((unsigned short)v10[e]), val);
                val = fmaf(w11, bf2f((unsigned short)v11[e]), val);
                r[e] = (short)f2bf(val);
            }
            *(short8v*)&Bs[(pr * 9 + kc) * 8] = r;
        }
        __syncthreads();
#pragma unroll
        for (int ks = 0; ks < 2; ks++) {
            short8v a[4], bf[2];
#pragma unroll
            for (int i = 0; i < 4; i++)
                a[i] = *(const short8v*)&As[(((ks * 4 + quad) * 256) + w * 64 + i * 16 + r15) * 8];
#pragma unroll
            for (int j = 0; j < 2; j++)
                bf[j] = *(const short8v*)&Bs[((j * 16 + r15) * 9 + ks * 4 + quad) * 8];
#pragma unroll
            for (int i = 0; i < 4; i++)
#pragma unroll
                for (int j = 0; j < 2; j++)
                    acc[i][j] = __builtin_amdgcn_mfma_f32_16x16x32_bf16(a[i], bf[j], acc[i][j], 0, 0, 0);
        }
        __syncthreads();
    }
    // epilogue: relu -> bf16 ta (C/D map: col=lane&15, row=quad*4+reg)
#pragma unroll
    for (int i = 0; i < 4; i++) {
        const int m = w * 64 + i * 16 + quad * 4;
#pragma unroll
        for (int j = 0; j < 2; j++) {
            const int n = n0 + j * 16 + r15;
            ushort4 st;
            st.x = f2bf(fmaxf(acc[i][j][0], 0.f));
            st.y = f2bf(fmaxf(acc[i][j][1], 0.f));
            st.z = f2bf(fmaxf(acc[i][j][2], 0.f));
            st.w = f2bf(fmaxf(acc[i][j][3], 0.f));
            *(ushort4*)(tacf + (size_t)n * CC + m) = st;
        }
    }
}

// ---- heads2 (R5-verbatim): cls/bbox from ta_cf (fp32 acc) ------------------
__global__ __launch_bounds__(256) void heads2_kernel(
    const unsigned short* __restrict__ tacf,
    const float* __restrict__ cls_w, const float* __restrict__ cls_b,
    const float* __restrict__ bbox_w, const float* __restrict__ bbox_b,
    float* __restrict__ out)
{
    const int p = blockIdx.x * 256 + threadIdx.x;
    const int b = blockIdx.y;
    const unsigned short* row = tacf + (size_t)(b * HWP + p) * CC;
    float ac = 0.f, a0 = 0.f, a1 = 0.f, a2 = 0.f, a3 = 0.f;
    for (int c = 0; c < CC; c += 8) {
        short8v v = *(const short8v*)&row[c];
#pragma unroll
        for (int k = 0; k < 8; k++) {
            const float fv = bf2f((unsigned short)v[k]);
            ac = fmaf(cls_w[c + k], fv, ac);
            a0 = fmaf(bbox_w[c + k], fv, a0);
            a1 = fmaf(bbox_w[CC + c + k], fv, a1);
            a2 = fmaf(bbox_w[2 * CC + c + k], fv, a2);
            a3 = fmaf(bbox_w[3 * CC + c + k], fv, a3);
        }
    }
    out[OUT_LOGITS + b * HWP + p] = ac + cls_b[0];
    out[OUT_BBOX + (b * 4 + 0) * HWP + p] = a0 + bbox_b[0];
    out[OUT_BBOX + (b * 4 + 1) * HWP + p] = a1 + bbox_b[1];
    out[OUT_BBOX + (b * 4 + 2) * HWP + p] = a2 + bbox_b[2];
    out[OUT_BBOX + (b * 4 + 3) * HWP + p] = a3 + bbox_b[3];
}

// ----------------------------------------------------------------------------
extern "C" void kernel_launch(void* const* d_in, const int* in_sizes, int n_in,
                              void* d_out, int out_size, void* d_ws, size_t ws_size,
                              hipStream_t stream)
{
    const float* feature  = (const float*)d_in[0];
    const float* conv_w   = (const float*)d_in[1];
    const float* conv_b   = (const float*)d_in[2];
    const float* loc_w    = (const float*)d_in[3];
    const float* loc_b    = (const float*)d_in[4];
    const float* shape_w  = (const float*)d_in[5];
    const float* shape_b  = (const float*)d_in[6];
    const float* offset_w = (const float*)d_in[7];
    const float* adapt_w  = (const float*)d_in[8];
    const float* cls_w    = (const float*)d_in[9];
    const float* cls_b    = (const float*)d_in[10];
    const float* bbox_w   = (const float*)d_in[11];
    const float* bbox_b   = (const float*)d_in[12];
    float* out = (float*)d_out;

    // workspace partition (~21 MB)
    float*          s0s1 = (float*)d_ws;                           // NTOT float2
    unsigned short* tcf  = (unsigned short*)(s0s1 + 2 * NTOT);     // NTOT*CC bf16
    unsigned short* fcf  = tcf + (size_t)NTOT * CC;                // NTOT*CC bf16
    unsigned short* tacf = fcf;   // alias: f_cf dead after gemm1
    unsigned short* W1   = fcf + (size_t)NTOT * CC;                // CC*K1 bf16
    unsigned short* W2   = W1 + (size_t)CC * K1;                   // CC*K1 bf16
    unsigned short* zp   = W2 + (size_t)CC * K1;                   // 1024 zeros

    prep_kernel<<<(CC * K1 + 255) / 256, 256, 0, stream>>>(conv_w, adapt_w, W1, W2, zp);
    transpose_kernel<<<dim3(HWP / 64, 4, BB), 256, 0, stream>>>(feature, fcf);
    gemm1_kernel<<<dim3(NTOT / 64, 2), 256, 0, stream>>>(W1, fcf, conv_b, zp, tcf);
    heads1_kernel<<<dim3(HWP / 256, BB), 256, 0, stream>>>(
        tcf, loc_w, loc_b, shape_w, shape_b, out, s0s1);
    gemm2_fused_kernel<<<dim3(NTOT / 32), 256, 0, stream>>>(
        W2, tcf, s0s1, offset_w, tacf);
    heads2_kernel<<<dim3(HWP / 256, BB), 256, 0, stream>>>(
        tacf, cls_w, cls_b, bbox_w, bbox_b, out);
}

// Round 9
// 316.528 us; speedup vs baseline: 1.0639x; 1.0639x over previous
//
#include <hip/hip_runtime.h>
#include <hip/hip_bf16.h>

// Problem constants
#define BB 2
#define CC 256
#define HH 96
#define WW 96
#define HWP (HH*WW)        // 9216
#define NTOT (BB*HWP)      // 18432 flattened (b,p)
#define K1 2304            // 256*9, GEMM K for both convs
#define NKT 36             // K1/64 k-steps
#define KHS 18             // k-steps per split-K half (gemm2)

// d_out layout: logits[2,1,96,96], bbox[2,4,96,96], shape[2,2,96,96], loc[2,1,96,96]
#define OUT_LOGITS 0
#define OUT_BBOX   (2*1*HWP)
#define OUT_SHAPE  (OUT_BBOX + 2*4*HWP)
#define OUT_LOC    (OUT_SHAPE + 2*2*HWP)

typedef __attribute__((ext_vector_type(8))) short short8v;   // 8 bf16 (4 VGPRs)
typedef __attribute__((ext_vector_type(4))) float f32x4;

typedef const __attribute__((address_space(1))) void* gptr_t;
typedef __attribute__((address_space(3))) void* lptr_t;
#define GLOAD16(g, l) __builtin_amdgcn_global_load_lds((gptr_t)(g), (lptr_t)(l), 16, 0, 0)

__device__ __forceinline__ float bf2f(unsigned short u) {
    return __uint_as_float(((unsigned)u) << 16);
}
__device__ __forceinline__ unsigned short f2bf(float f) {
    unsigned u = __float_as_uint(f);
    u += 0x7FFFu + ((u >> 16) & 1u);           // round-to-nearest-even
    return (unsigned short)(u >> 16);
}

// ------- prep: weights -> bf16, BOTH in k = kk*256+ci order; zero page ------
__global__ __launch_bounds__(256) void prep_kernel(
    const float* __restrict__ conv_w, const float* __restrict__ adapt_w,
    unsigned short* __restrict__ W1, unsigned short* __restrict__ W2,
    unsigned short* __restrict__ zp)
{
    const int t = blockIdx.x * 256 + threadIdx.x;
    if (t < 1024) zp[t] = 0;                    // zero page (ws is re-poisoned!)
    if (t < CC * K1) {
        const int co = t / K1, r = t % K1;
        const int kk = r >> 8, ci = r & 255;    // k = kk*256+ci
        W1[t] = f2bf(conv_w[co * K1 + ci * 9 + kk]);
        W2[t] = f2bf(adapt_w[co * K1 + ci * 9 + kk]);
    }
}

// ------------- transpose feature [b][c][p] fp32 -> f_cf [b][p][c] bf16 ------
// grid (144, 4, 2): channel-group split across blockIdx.y (pure permutation).
__global__ __launch_bounds__(256) void transpose_kernel(
    const float* __restrict__ f, unsigned short* __restrict__ fcf)
{
    __shared__ unsigned short tile[64][66];     // +2 pad: conflict-free col reads
    const int p0 = blockIdx.x * 64;
    const int cc = blockIdx.y;
    const int b  = blockIdx.z;
    const int tx = threadIdx.x & 63, ty = threadIdx.x >> 6;
#pragma unroll
    for (int ii = 0; ii < 16; ii++) {
        const int cl = ii * 4 + ty;
        tile[cl][tx] = f2bf(f[((size_t)b * CC + cc * 64 + cl) * HWP + p0 + tx]);
    }
    __syncthreads();
#pragma unroll
    for (int ii = 0; ii < 16; ii++) {
        const int pl = ii * 4 + ty;
        fcf[((size_t)(b * HWP + p0 + pl)) * CC + cc * 64 + tx] = tile[tx][pl];
    }
}

// --------- GEMM1 (R8-verbatim, passed 3x): t = relu(W1 x im2col + bias) -----
// 128M x 64N tile, BK=64, 4 waves (2x2), 16x16x32 MFMA, global_load_lds.
__global__ __launch_bounds__(256) void gemm1_kernel(
    const unsigned short* __restrict__ W1, const unsigned short* __restrict__ fcf,
    const float* __restrict__ bias, const unsigned short* __restrict__ zp,
    unsigned short* __restrict__ tcf)
{
    __shared__ short As[8192];                  // 128 rows x 64 k = 16 KB
    __shared__ short Bs[4096];                  // 64 rows x 64 k = 8 KB
    const int tid  = threadIdx.x;
    const int lane = tid & 63, w = tid >> 6;
    const int quad = lane >> 4, r15 = lane & 15;
    const int n0  = blockIdx.x * 64;            // flattened (b,p); 9216%64==0
    const int co0 = blockIdx.y * 128;
    const int wm = w >> 1, wn = w & 1;

    const int nb = n0 + lane;
    const int b  = nb / HWP;
    const int p  = nb - b * HWP;
    const int y = p / WW, x = p % WW;

    f32x4 acc[4][2];
#pragma unroll
    for (int i = 0; i < 4; i++)
#pragma unroll
        for (int j = 0; j < 2; j++) acc[i][j] = (f32x4){0.f, 0.f, 0.f, 0.f};

    for (int kt = 0; kt < NKT; kt++) {
        const int k0 = kt * 64;
#pragma unroll
        for (int i = 0; i < 4; i++) {           // A: 4 chunks/thread
            const int kc    = w * 2 + (i >> 1);
            const int row   = ((i & 1) << 6) + lane;
            const int sbase = w * 256 + i * 64;
            GLOAD16(W1 + (size_t)(co0 + row) * K1 + k0 + kc * 8, &As[sbase * 8]);
        }
#pragma unroll
        for (int i = 0; i < 2; i++) {           // B: 2 chunks/thread, implicit im2col
            const int kc    = w * 2 + i;
            const int sbase = w * 128 + i * 64;
            const int k   = k0 + kc * 8;
            const int kk  = k >> 8;
            const int ci0 = k & 255;
            const int yy = y + kk / 3 - 1, xx = x + kk % 3 - 1;
            const bool ok = (yy >= 0) && (yy < HH) && (xx >= 0) && (xx < WW);
            const unsigned short* gb = ok
                ? fcf + ((size_t)(b * HWP + yy * WW + xx)) * CC + ci0
                : zp;
            GLOAD16(gb, &Bs[sbase * 8]);
        }
        __syncthreads();
#pragma unroll
        for (int ks = 0; ks < 2; ks++) {
            short8v a[4], bf[2];
#pragma unroll
            for (int i = 0; i < 4; i++)
                a[i] = *(const short8v*)&As[(((ks * 4 + quad) * 128) + wm * 64 + i * 16 + r15) * 8];
#pragma unroll
            for (int j = 0; j < 2; j++)
                bf[j] = *(const short8v*)&Bs[(((ks * 4 + quad) * 64) + wn * 32 + j * 16 + r15) * 8];
#pragma unroll
            for (int i = 0; i < 4; i++)
#pragma unroll
                for (int j = 0; j < 2; j++)
                    acc[i][j] = __builtin_amdgcn_mfma_f32_16x16x32_bf16(a[i], bf[j], acc[i][j], 0, 0, 0);
        }
        __syncthreads();
    }
    // epilogue: bias + relu -> t_cf[n][c] bf16 (C/D map: col=lane&15, row=quad*4+reg)
#pragma unroll
    for (int i = 0; i < 4; i++) {
        const int m = co0 + wm * 64 + i * 16 + quad * 4;
        const float b0 = bias[m], b1 = bias[m + 1], b2 = bias[m + 2], b3 = bias[m + 3];
#pragma unroll
        for (int j = 0; j < 2; j++) {
            const int n = n0 + wn * 32 + j * 16 + r15;
            ushort4 st;
            st.x = f2bf(fmaxf(acc[i][j][0] + b0, 0.f));
            st.y = f2bf(fmaxf(acc[i][j][1] + b1, 0.f));
            st.z = f2bf(fmaxf(acc[i][j][2] + b2, 0.f));
            st.w = f2bf(fmaxf(acc[i][j][3] + b3, 0.f));
            *(ushort4*)(tcf + (size_t)n * CC + m) = st;
        }
    }
}

// ---- heads1: same per-pixel arithmetic as R5/R8, regridded 288 x 64thr -----
__global__ __launch_bounds__(64) void heads1_kernel(
    const unsigned short* __restrict__ tcf,
    const float* __restrict__ loc_w, const float* __restrict__ loc_b,
    const float* __restrict__ shape_w, const float* __restrict__ shape_b,
    float* __restrict__ out, float* __restrict__ s0s1)
{
    const int n = blockIdx.x * 64 + threadIdx.x;
    const int b = n / HWP, p = n - b * HWP;
    const unsigned short* row = tcf + (size_t)n * CC;
    float aloc = 0.f, s0 = 0.f, s1 = 0.f;
    for (int c = 0; c < CC; c += 8) {
        short8v v = *(const short8v*)&row[c];
#pragma unroll
        for (int k = 0; k < 8; k++) {
            const float fv = bf2f((unsigned short)v[k]);
            aloc = fmaf(loc_w[c + k], fv, aloc);
            s0   = fmaf(shape_w[c + k], fv, s0);
            s1   = fmaf(shape_w[CC + c + k], fv, s1);
        }
    }
    aloc += loc_b[0]; s0 += shape_b[0]; s1 += shape_b[1];
    out[OUT_LOC + n] = aloc;
    out[OUT_SHAPE + (b * 2 + 0) * HWP + p] = s0;
    out[OUT_SHAPE + (b * 2 + 1) * HWP + p] = s1;
    *(float2*)&s0s1[2 * n] = make_float2(s0, s1);
}

// ---- fused GEMM2, split-K=2: partial(kh) = W2[:, Kh] x sampled B(Kh) -------
// M=256 x N=32, BK=64; block (n0, kh) does k-steps [18kh, 18kh+18).
// Sampling math, LDS layouts, MFMA inner loop VERBATIM R8 (passed).
// Output: fp32 partials, NO relu, to disjoint pta[kh] buffers.
__global__ __launch_bounds__(256) void gemm2_fused_kernel(
    const unsigned short* __restrict__ W2, const unsigned short* __restrict__ tcf,
    const float* __restrict__ s0s1, const float* __restrict__ offset_w,
    float* __restrict__ pta0, float* __restrict__ pta1)
{
    __shared__ short As[16384];                 // 8 kc-chunks x 256 rows x 16B = 32 KB
    __shared__ short Bs[32 * 9 * 8];            // padded layout, 4.6 KB
    const int tid  = threadIdx.x;
    const int lane = tid & 63, w = tid >> 6;
    const int quad = lane >> 4, r15 = lane & 15;
    const int n0  = blockIdx.x * 32;
    const int kh  = blockIdx.y;                 // split-K half

    // sampler mapping: thread -> (pixel pr, 8-ch chunk kc)
    const int pr = tid >> 3, kc = tid & 7;
    const int nb = n0 + pr;
    const int b  = nb / HWP;
    const int p  = nb - b * HWP;
    const int y = p / WW, x = p % WW;
    const float2 s01 = *(const float2*)&s0s1[2 * nb];
    const unsigned short* tb = tcf + (size_t)b * HWP * CC;

    f32x4 acc[4][2];
#pragma unroll
    for (int i = 0; i < 4; i++)
#pragma unroll
        for (int j = 0; j < 2; j++) acc[i][j] = (f32x4){0.f, 0.f, 0.f, 0.f};

    for (int kt = kh * KHS; kt < kh * KHS + KHS; kt++) {
        const int k0 = kt * 64;
        const int kk = kt >> 2, g = kt & 3;
        // A: wave w stages kc-chunks {2w, 2w+1} x all 256 rows (slot = kc*256+row)
#pragma unroll
        for (int i = 0; i < 8; i++) {
            const int kca   = w * 2 + (i >> 2);
            const int rr    = (i & 3) * 64;          // + lane via DMA
            const int sbase = kca * 256 + rr;
            GLOAD16(W2 + (size_t)(rr + lane) * K1 + k0 + kca * 8, &As[sbase * 8]);
        }
        // B: bilinear sample of 8 channels (R5/R8-verbatim math)
        {
            const int o_dy = (g * 9 + kk) * 2, o_dx = o_dy + 1;
            const float dy = fmaf(offset_w[o_dy * 2], s01.x, offset_w[o_dy * 2 + 1] * s01.y);
            const float dx = fmaf(offset_w[o_dx * 2], s01.x, offset_w[o_dx * 2 + 1] * s01.y);
            const float py = (float)(y + kk / 3 - 1) + dy;
            const float px = (float)(x + kk % 3 - 1) + dx;
            const float y0f = floorf(py), x0f = floorf(px);
            const float wy = py - y0f, wx = px - x0f;
            const int y0 = (int)y0f, x0 = (int)x0f;
            const int y1 = y0 + 1, x1 = x0 + 1;
            const bool vy0 = (y0 >= 0) && (y0 < HH), vy1 = (y1 >= 0) && (y1 < HH);
            const bool vx0 = (x0 >= 0) && (x0 < WW), vx1 = (x1 >= 0) && (x1 < WW);
            const int y0c = min(max(y0, 0), HH - 1), y1c = min(max(y1, 0), HH - 1);
            const int x0c = min(max(x0, 0), WW - 1), x1c = min(max(x1, 0), WW - 1);
            const float w00 = (vy0 && vx0) ? (1.f - wy) * (1.f - wx) : 0.f;
            const float w01 = (vy0 && vx1) ? (1.f - wy) * wx         : 0.f;
            const float w10 = (vy1 && vx0) ? wy * (1.f - wx)         : 0.f;
            const float w11 = (vy1 && vx1) ? wy * wx                 : 0.f;
            const int ch = g * 64 + kc * 8;
            const short8v v00 = *(const short8v*)(tb + (size_t)(y0c * WW + x0c) * CC + ch);
            const short8v v01 = *(const short8v*)(tb + (size_t)(y0c * WW + x1c) * CC + ch);
            const short8v v10 = *(const short8v*)(tb + (size_t)(y1c * WW + x0c) * CC + ch);
            const short8v v11 = *(const short8v*)(tb + (size_t)(y1c * WW + x1c) * CC + ch);
            short8v r;
#pragma unroll
            for (int e = 0; e < 8; e++) {
                float val = w00 * bf2f((unsigned short)v00[e]);
                val = fmaf(w01, bf2f((unsigned short)v01[e]), val);
                val = fmaf(w10, bf2f((unsigned short)v10[e]), val);
                val = fmaf(w11, bf2f((unsigned short)v11[e]), val);
                r[e] = (short)f2bf(val);
            }
            *(short8v*)&Bs[(pr * 9 + kc) * 8] = r;
        }
        __syncthreads();
#pragma unroll
        for (int ks = 0; ks < 2; ks++) {
            short8v a[4], bf[2];
#pragma unroll
            for (int i = 0; i < 4; i++)
                a[i] = *(const short8v*)&As[(((ks * 4 + quad) * 256) + w * 64 + i * 16 + r15) * 8];
#pragma unroll
            for (int j = 0; j < 2; j++)
                bf[j] = *(const short8v*)&Bs[((j * 16 + r15) * 9 + ks * 4 + quad) * 8];
#pragma unroll
            for (int i = 0; i < 4; i++)
#pragma unroll
                for (int j = 0; j < 2; j++)
                    acc[i][j] = __builtin_amdgcn_mfma_f32_16x16x32_bf16(a[i], bf[j], acc[i][j], 0, 0, 0);
        }
        __syncthreads();
    }
    // epilogue: fp32 partial, no relu (C/D map: col=lane&15, row=quad*4+reg)
    float* pta = kh ? pta1 : pta0;
#pragma unroll
    for (int i = 0; i < 4; i++) {
        const int m = w * 64 + i * 16 + quad * 4;
#pragma unroll
        for (int j = 0; j < 2; j++) {
            const int n = n0 + j * 16 + r15;
            *(f32x4*)(pta + (size_t)n * CC + m) = acc[i][j];
        }
    }
}

// ---- heads2: cls/bbox from relu(pta0+pta1), fp32 all the way ---------------
__global__ __launch_bounds__(64) void heads2_kernel(
    const float* __restrict__ pta0, const float* __restrict__ pta1,
    const float* __restrict__ cls_w, const float* __restrict__ cls_b,
    const float* __restrict__ bbox_w, const float* __restrict__ bbox_b,
    float* __restrict__ out)
{
    const int n = blockIdx.x * 64 + threadIdx.x;
    const int b = n / HWP, p = n - b * HWP;
    const float* r0 = pta0 + (size_t)n * CC;
    const float* r1 = pta1 + (size_t)n * CC;
    float ac = 0.f, a0 = 0.f, a1 = 0.f, a2 = 0.f, a3 = 0.f;
    for (int c = 0; c < CC; c += 4) {
        const float4 u = *(const float4*)&r0[c];
        const float4 v = *(const float4*)&r1[c];
        float fv[4];
        fv[0] = fmaxf(u.x + v.x, 0.f);
        fv[1] = fmaxf(u.y + v.y, 0.f);
        fv[2] = fmaxf(u.z + v.z, 0.f);
        fv[3] = fmaxf(u.w + v.w, 0.f);
#pragma unroll
        for (int k = 0; k < 4; k++) {
            ac = fmaf(cls_w[c + k], fv[k], ac);
            a0 = fmaf(bbox_w[c + k], fv[k], a0);
            a1 = fmaf(bbox_w[CC + c + k], fv[k], a1);
            a2 = fmaf(bbox_w[2 * CC + c + k], fv[k], a2);
            a3 = fmaf(bbox_w[3 * CC + c + k], fv[k], a3);
        }
    }
    out[OUT_LOGITS + n] = ac + cls_b[0];
    out[OUT_BBOX + (b * 4 + 0) * HWP + p] = a0 + bbox_b[0];
    out[OUT_BBOX + (b * 4 + 1) * HWP + p] = a1 + bbox_b[1];
    out[OUT_BBOX + (b * 4 + 2) * HWP + p] = a2 + bbox_b[2];
    out[OUT_BBOX + (b * 4 + 3) * HWP + p] = a3 + bbox_b[3];
}

// ----------------------------------------------------------------------------
extern "C" void kernel_launch(void* const* d_in, const int* in_sizes, int n_in,
                              void* d_out, int out_size, void* d_ws, size_t ws_size,
                              hipStream_t stream)
{
    const float* feature  = (const float*)d_in[0];
    const float* conv_w   = (const float*)d_in[1];
    const float* conv_b   = (const float*)d_in[2];
    const float* loc_w    = (const float*)d_in[3];
    const float* loc_b    = (const float*)d_in[4];
    const float* shape_w  = (const float*)d_in[5];
    const float* shape_b  = (const float*)d_in[6];
    const float* offset_w = (const float*)d_in[7];
    const float* adapt_w  = (const float*)d_in[8];
    const float* cls_w    = (const float*)d_in[9];
    const float* cls_b    = (const float*)d_in[10];
    const float* bbox_w   = (const float*)d_in[11];
    const float* bbox_b   = (const float*)d_in[12];
    float* out = (float*)d_out;

    // workspace partition (~59 MB)
    float*          s0s1 = (float*)d_ws;                           // NTOT float2
    unsigned short* tcf  = (unsigned short*)(s0s1 + 2 * NTOT);     // NTOT*CC bf16
    unsigned short* fcf  = tcf + (size_t)NTOT * CC;                // NTOT*CC bf16
    unsigned short* W1   = fcf + (size_t)NTOT * CC;                // CC*K1 bf16
    unsigned short* W2   = W1 + (size_t)CC * K1;                   // CC*K1 bf16
    unsigned short* zp   = W2 + (size_t)CC * K1;                   // 1024 zeros
    float*          pta0 = (float*)(zp + 1024);                    // NTOT*CC fp32
    float*          pta1 = pta0 + (size_t)NTOT * CC;               // NTOT*CC fp32

    prep_kernel<<<(CC * K1 + 255) / 256, 256, 0, stream>>>(conv_w, adapt_w, W1, W2, zp);
    transpose_kernel<<<dim3(HWP / 64, 4, BB), 256, 0, stream>>>(feature, fcf);
    gemm1_kernel<<<dim3(NTOT / 64, 2), 256, 0, stream>>>(W1, fcf, conv_b, zp, tcf);
    heads1_kernel<<<dim3(NTOT / 64), 64, 0, stream>>>(
        tcf, loc_w, loc_b, shape_w, shape_b, out, s0s1);
    gemm2_fused_kernel<<<dim3(NTOT / 32, 2), 256, 0, stream>>>(
        W2, tcf, s0s1, offset_w, pta0, pta1);
    heads2_kernel<<<dim3(NTOT / 64), 64, 0, stream>>>(
        pta0, pta1, cls_w, cls_b, bbox_w, bbox_b, out);
}